// Round 4
// baseline (5625.137 us; speedup 1.0000x reference)
//
#include <hip/hip_runtime.h>
#include <hip/hip_bf16.h>
#include <cstdint>
#include <cstddef>

// LSTM encoder: B=64, T=512, D=256, UNITS=1024, gates G=4096 (i|f|g|o).
// Persistent: 256 WGs x 256 thr, WG owns 4 units. R3 lesson: relaxed-atomic h
// loads don't pipeline (16 serial L3 hops ~5us/step). R4: h staged to LDS via
// global_load_lds aux=SC1 (async, bypassing), XOR-swizzled hbuf layout for
// conflict-free ds_read_b128. Per-WAVE flags (wave w touches only rows
// [16w,16w+16)) -> no __syncthreads in the step loop. out stores after flag.

#define NWG    256
#define KSTEPS 40
#define SEQ_N  33554432ull   // 64*512*1024

typedef __attribute__((ext_vector_type(8))) short short8;
typedef __attribute__((ext_vector_type(4))) float floatx4;

static __device__ __forceinline__ short f2bf(float f) {
  __hip_bfloat16 h = __float2bfloat16(f);
  return *reinterpret_cast<short*>(&h);
}
static __device__ __forceinline__ float sigm(float x) { return 1.f / (1.f + __expf(-x)); }
static __device__ __forceinline__ float tanh_fast(float x) {
  float xc = fminf(fmaxf(x, -15.f), 15.f);
  float e  = __expf(2.f * xc);
  return (e - 1.f) / (e + 1.f);
}

// async global->LDS, 16B/lane, SC1 (device-coherent read at MALL)
static __device__ __forceinline__ void load_lds16(const void* g, void* l) {
  __builtin_amdgcn_global_load_lds((const __attribute__((address_space(1))) void*)g,
                                   (__attribute__((address_space(3))) void*)l,
                                   16, 0, 16 /*SC1*/);
}

// ---- prep: pack [U;W] into per-WG MFMA B-fragment order, bf16 (as R3) ----
__global__ void pack_weights(const float* __restrict__ W, const float* __restrict__ U,
                             short* __restrict__ upack) {
  int idx  = blockIdx.x * 256 + threadIdx.x;   // 0 .. 256*40*64-1
  int lane = idx & 63;
  int kk   = (idx >> 6) % KSTEPS;
  int wg   = idx / (KSTEPS * 64);
  int quad = lane >> 4, n = lane & 15;
  int col  = (n >> 2) * 1024 + wg * 4 + (n & 3);
  int k0   = kk * 32 + quad * 8;
  short8 v;
#pragma unroll
  for (int j = 0; j < 8; ++j) {
    int k = k0 + j;
    float f = (k < 1024) ? U[(size_t)k * 4096 + col] : W[(size_t)(k - 1024) * 4096 + col];
    v[j] = f2bf(f);
  }
  *reinterpret_cast<short8*>(upack + (size_t)idx * 8) = v;
}

__global__ void convert_x(const float* __restrict__ x, short* __restrict__ xbf) {
  int idx = blockIdx.x * 256 + threadIdx.x;
  const float* xp = x + (size_t)idx * 8;
  short8 v;
#pragma unroll
  for (int j = 0; j < 8; ++j) v[j] = f2bf(xp[j]);
  *reinterpret_cast<short8*>(xbf + (size_t)idx * 8) = v;
}

// zero h0 + flags at the coherence point (bypassing stores)
__global__ void init_state(unsigned int* __restrict__ hbuf32,
                           int* __restrict__ arrive) {
  int idx = blockIdx.x * 256 + threadIdx.x;    // 272 blocks: 65536 + 4096
  if (idx < 65536)
    __hip_atomic_store(&hbuf32[idx], 0u, __ATOMIC_RELAXED, __HIP_MEMORY_SCOPE_AGENT);
  else if (idx < 65536 + 4096)
    __hip_atomic_store(&arrive[idx - 65536], 0, __ATOMIC_RELAXED, __HIP_MEMORY_SCOPE_AGENT);
}

// ---- persistent stepper ----
__global__ __launch_bounds__(256, 1) void lstm_persist(
    const short* __restrict__ xbf,    // [64][512][256] bf16
    const short* __restrict__ upack,  // packed B frags, 20480 shorts/WG
    const float* __restrict__ bias,   // [4096] f32
    char*  __restrict__ hbase,        // 2 x 131072B swizzled h buffers
    int*   __restrict__ arrive,       // [4 waves][256 wg] flags, 16B padded
    float* __restrict__ out)
{
  __shared__ short wlds[14336];       // 28672B: U-frag iters 0..13
  __shared__ short hlds[65536];       // 131072B: swizzled h, per-wave 32KB slices

  const int wg   = blockIdx.x;
  const int tid  = threadIdx.x;
  const int wave = tid >> 6;
  const int lane = tid & 63;
  const int quad = lane >> 4;
  const int l15  = lane & 15;
  const int g    = l15 >> 2;                 // this lane's gate-row selector
  const int j    = l15 & 3;                  // unit-in-wg
  const int arow = wave * 16 + l15;          // A-frag batch row
  const int grow = wave * 16 + quad * 4 + g; // this lane's (batch) after exchange
  const int unit = wg * 4 + j;
  const float bi = bias[unit];
  const float bfv = bias[1024 + unit];
  const float bg = bias[2048 + unit];
  const float bo = bias[3072 + unit];
  float creg = 0.f;

  // stage U-frag iters 0..13 into LDS (plain cached loads, once)
  {
    const short* src = upack + (size_t)wg * 20480;
#pragma unroll
    for (int i = 0; i < 7; ++i) {
      int idx = i * 256 + tid;
      *reinterpret_cast<short8*>(wlds + idx * 8) =
          *reinterpret_cast<const short8*>(src + idx * 8);
    }
  }
  // iters 14..19 B-frags -> VGPRs (wv[0..3]=U iters 14,15; wv[4..11]=W iters 16..19)
  short8 wv[12];
#pragma unroll
  for (int it = 0; it < 6; ++it) {
    const short* p = upack + (size_t)wg * 20480 + (14 + it) * 1024 + lane * 8;
    wv[it * 2]     = *reinterpret_cast<const short8*>(p);
    wv[it * 2 + 1] = *reinterpret_cast<const short8*>(p + 512);
  }
  __syncthreads();

  const short* xrow = xbf + (size_t)arow * 512 * 256 + quad * 8;

  auto compute_x = [&](int t, floatx4& a0o, floatx4& a1o) {
    floatx4 a0 = {0.f, 0.f, 0.f, 0.f};
    floatx4 a1 = {0.f, 0.f, 0.f, 0.f};
    const short* xp = xrow + t * 256;
#pragma unroll
    for (int it = 0; it < 4; ++it) {
      short8 av0 = *reinterpret_cast<const short8*>(xp);
      short8 av1 = *reinterpret_cast<const short8*>(xp + 32);
      xp += 64;
      a0 = __builtin_amdgcn_mfma_f32_16x16x32_bf16(av0, wv[4 + it * 2], a0, 0, 0, 0);
      a1 = __builtin_amdgcn_mfma_f32_16x16x32_bf16(av1, wv[5 + it * 2], a1, 0, 0, 0);
    }
    a0o = a0; a1o = a1;
  };

  floatx4 xa0, xa1;
  compute_x(0, xa0, xa1);

  const int rx  = l15 & 7;                       // swizzle key (row & 7)
  char* hl      = (char*)hlds + wave * 32768;    // this wave's LDS slice
  const int hbo = l15 * 2048;                    // row byte base in slice
  const int swz_chunk = ((wg >> 1) ^ (grow & 7));          // producer store chunk
  const int hstore_off = swz_chunk * 16 + ((wg & 1) * 4 + j) * 2;
  int* myflag = arrive + (wave * 256 + wg) * 4;
  const int* fb = arrive + wave * 1024 + lane * 16;        // 4 flags this lane polls

  for (int t = 0; t < 512; ++t) {
    const char* hsrc = hbase + ((size_t)(t & 1) << 17);
    char*       hdst = hbase + ((size_t)((t + 1) & 1) << 17);

    // ---- stage this wave's 16 h-rows (32KB) into LDS, async bypassing ----
    {
      const char* gp = hsrc + wave * 32768 + lane * 16;
#pragma unroll
      for (int i = 0; i < 32; ++i)
        load_lds16(gp + i * 1024, hl + i * 1024);
    }
    __atomic_signal_fence(__ATOMIC_SEQ_CST);
    __builtin_amdgcn_s_waitcnt(0);
    __atomic_signal_fence(__ATOMIC_SEQ_CST);

    // ---- z = h@U + x@W (acc pre-seeded with x part) ----
    floatx4 acc0 = xa0, acc1 = xa1;
#pragma unroll
    for (int it = 0; it < 14; ++it) {
      int c0 = (((it * 8 + quad) ^ rx) << 4);
      short8 a0 = *reinterpret_cast<const short8*>(hl + hbo + c0);
      short8 a1 = *reinterpret_cast<const short8*>(hl + hbo + (c0 ^ 64));
      short8 b0 = *reinterpret_cast<const short8*>(wlds + it * 1024 + lane * 8);
      short8 b1 = *reinterpret_cast<const short8*>(wlds + it * 1024 + 512 + lane * 8);
      acc0 = __builtin_amdgcn_mfma_f32_16x16x32_bf16(a0, b0, acc0, 0, 0, 0);
      acc1 = __builtin_amdgcn_mfma_f32_16x16x32_bf16(a1, b1, acc1, 0, 0, 0);
    }
#pragma unroll
    for (int it = 14; it < 16; ++it) {
      int c0 = (((it * 8 + quad) ^ rx) << 4);
      short8 a0 = *reinterpret_cast<const short8*>(hl + hbo + c0);
      short8 a1 = *reinterpret_cast<const short8*>(hl + hbo + (c0 ^ 64));
      acc0 = __builtin_amdgcn_mfma_f32_16x16x32_bf16(a0, wv[(it - 14) * 2], acc0, 0, 0, 0);
      acc1 = __builtin_amdgcn_mfma_f32_16x16x32_bf16(a1, wv[(it - 14) * 2 + 1], acc1, 0, 0, 0);
    }
    acc0 = acc0 + acc1;

    // ---- gate exchange in-register: z[G] for (b=grow, unit) ----
    float z[4];
#pragma unroll
    for (int G = 0; G < 4; ++G) {
      int src = quad * 16 + G * 4 + j;
      float t0 = __shfl(acc0[0], src, 64);
      float t1 = __shfl(acc0[1], src, 64);
      float t2 = __shfl(acc0[2], src, 64);
      float t3 = __shfl(acc0[3], src, 64);
      z[G] = (g == 0) ? t0 : (g == 1) ? t1 : (g == 2) ? t2 : t3;
    }
    float ig = sigm(z[0] + bi), fg = sigm(z[1] + bfv);
    float gg = tanh_fast(z[2] + bg), og = sigm(z[3] + bo);
    float cn = fg * creg + ig * gg;
    creg = cn;
    float hn = og * tanh_fast(cn);

    // ---- h store (swizzled, bypassing, u32-paired) ----
    float hn_nb = __shfl_xor(hn, 1, 64);
    if ((j & 1) == 0) {
      unsigned int val = (unsigned int)(unsigned short)f2bf(hn) |
                         ((unsigned int)(unsigned short)f2bf(hn_nb) << 16);
      __hip_atomic_store((unsigned int*)(hdst + grow * 2048 + hstore_off), val,
                         __ATOMIC_RELAXED, __HIP_MEMORY_SCOPE_AGENT);
    }

    if (t < 511) {
      __atomic_signal_fence(__ATOMIC_SEQ_CST);
      __builtin_amdgcn_s_waitcnt(0);          // h stores at coherence point
      __atomic_signal_fence(__ATOMIC_SEQ_CST);
      if (lane == 0)
        __hip_atomic_store(myflag, t + 1, __ATOMIC_RELAXED, __HIP_MEMORY_SCOPE_AGENT);
      out[((size_t)grow * 512 + t) * 1024 + unit] = hn;   // after flag: not on critical path
      compute_x(t + 1, xa0, xa1);
      for (;;) {
        int f0 = __hip_atomic_load(fb + 0,  __ATOMIC_RELAXED, __HIP_MEMORY_SCOPE_AGENT);
        int f1 = __hip_atomic_load(fb + 4,  __ATOMIC_RELAXED, __HIP_MEMORY_SCOPE_AGENT);
        int f2 = __hip_atomic_load(fb + 8,  __ATOMIC_RELAXED, __HIP_MEMORY_SCOPE_AGENT);
        int f3 = __hip_atomic_load(fb + 12, __ATOMIC_RELAXED, __HIP_MEMORY_SCOPE_AGENT);
        if (__all(f0 > t && f1 > t && f2 > t && f3 > t)) break;
        __builtin_amdgcn_s_sleep(1);
      }
      __atomic_signal_fence(__ATOMIC_SEQ_CST);
    } else {
      out[((size_t)grow * 512 + t) * 1024 + unit] = hn;
      out[SEQ_N + (size_t)grow * 1024 + unit] = hn;            // h_last
      out[SEQ_N + 65536 + (size_t)grow * 1024 + unit] = cn;    // c_last
    }
  }
}

extern "C" void kernel_launch(void* const* d_in, const int* in_sizes, int n_in,
                              void* d_out, int out_size, void* d_ws, size_t ws_size,
                              hipStream_t stream) {
  const float* x    = (const float*)d_in[0];
  const float* W    = (const float*)d_in[1];
  const float* U    = (const float*)d_in[2];
  const float* bias = (const float*)d_in[3];
  float* out = (float*)d_out;
  char* ws = (char*)d_ws;

  short* upack = (short*)ws;                      // 10,485,760 B
  short* xbf   = (short*)(ws + 10485760);         // 16,777,216 B
  char*  hbuf  = ws + 27262976;                   //    262,144 B (2 swizzled bufs)
  int*   arrive= (int*)(ws + 27525120);           //     16,384 B flag slots
  (void)in_sizes; (void)n_in; (void)out_size; (void)ws_size;

  init_state<<<272, 256, 0, stream>>>((unsigned int*)hbuf, arrive);
  pack_weights<<<2560, 256, 0, stream>>>(W, U, upack);
  convert_x<<<4096, 256, 0, stream>>>(x, xbf);
  lstm_persist<<<NWG, 256, 0, stream>>>(xbf, upack, bias, hbuf, arrive, out);
}